// Round 11
// baseline (156.695 us; speedup 1.0000x reference)
//
#include <hip/hip_runtime.h>

#define T_TEST 8192
#define BB 8
#define FF 100
#define HH 512

typedef __bf16 bf16x8 __attribute__((ext_vector_type(8)));
typedef float f32x16 __attribute__((ext_vector_type(16)));
typedef unsigned short u16;
typedef unsigned int u32;

__device__ __forceinline__ u16 f2bf(float f) {
    u32 u = __float_as_uint(f);
    u += 0x7fffu + ((u >> 16) & 1);   // RNE
    return (u16)(u >> 16);
}

__device__ __forceinline__ float nan2num(float v) {
    u32 u = __float_as_uint(v);
    if ((u & 0x7f800000u) == 0x7f800000u) {
        v = (u & 0x007fffffu) ? 0.f : ((u >> 31) ? -3.3895314e38f : 3.3895314e38f);
    }
    return v;
}

// ---- combined weight prep: 32x32x16 fragment-major layouts -------------
// B-frag: B[k][n], n = lane&31, k = (lane>>5)*8 + j, 8 bf16/lane.
// w1f frag idx: ((b*8  + ks)*16 + n32)*64 + lane   (ks 0..7; kernel uses 0..6)
// w2f frag idx: ((b*32 + ks)*16 + n32)*64 + lane   (ks 0..31)
__global__ void prep_w(const float* __restrict__ w1, const float* __restrict__ w2,
                       u16* __restrict__ w1f, u16* __restrict__ w2f) {
    int bid = blockIdx.x;
    if (bid < 256) {                      // w1f
        int t = bid * 256 + threadIdx.x;
        int lane = t & 63;
        int n32 = (t >> 6) & 15;
        int b = t >> 13;
        int n = n32 * 32 + (lane & 31);
        int kb = ((t >> 10) & 7) * 16 + (lane >> 5) * 8;
        u32 p[4];
#pragma unroll
        for (int jp = 0; jp < 4; ++jp) {
            int k0 = kb + jp * 2;
            float v0 = (k0 < FF)     ? w1[(b * FF + k0) * HH + n]     : 0.f;
            float v1 = (k0 + 1 < FF) ? w1[(b * FF + k0 + 1) * HH + n] : 0.f;
            p[jp] = (u32)f2bf(v0) | ((u32)f2bf(v1) << 16);
        }
        uint4 o = {p[0], p[1], p[2], p[3]};
        *(uint4*)(w1f + (size_t)t * 8) = o;
    } else {                              // w2f
        int t = (bid - 256) * 256 + threadIdx.x;
        int lane = t & 63;
        int n32 = (t >> 6) & 15;
        int b = t >> 15;
        int n = n32 * 32 + (lane & 31);
        int kb = ((t >> 10) & 31) * 16 + (lane >> 5) * 8;
        u32 p[4];
#pragma unroll
        for (int jp = 0; jp < 4; ++jp) {
            int k0 = kb + jp * 2;
            float v0 = w2[(b * HH + k0) * HH + n];
            float v1 = w2[(b * HH + k0 + 1) * HH + n];
            p[jp] = (u32)f2bf(v0) | ((u32)f2bf(v1) << 16);
        }
        uint4 o = {p[0], p[1], p[2], p[3]};
        *(uint4*)(w2f + (size_t)t * 8) = o;
    }
}

// ---- kernel A: layer 1 -> h1g (global, frag-major per 64-row tile) -----
// h1g tile layout: fi = ks*2+mi in [0,32), 1 KB frags; tile = 64 KB.
__global__ __launch_bounds__(512, 2) void l1_kernel(
    const float* __restrict__ x, const u16* __restrict__ w1f,
    const float* __restrict__ b1, u16* __restrict__ h1g) {
    __shared__ __align__(16) char lds[81920];
    u16* xf  = (u16*)lds;                  // x frags, 16 KB (fi = ks1*2+mi)
    u16* h1f = (u16*)(lds + 16384);        // h1 frags, 64 KB (fi = ks*2+mi)

    const int tid = threadIdx.x;
    const int b = blockIdx.x;              // batch -> XCD affinity
    const int m0 = blockIdx.y * 64;
    const int lane = tid & 63;
    const int ws = __builtin_amdgcn_readfirstlane(tid >> 6);
    const int l31 = lane & 31, lh = lane >> 5;
    const int n32b = ws * 2;

    const bf16x8* W1 = (const bf16x8*)w1f + (size_t)b * 8192;

    bf16x8 pa[2][2], pb[4][2];

    // B prologue: stages 0..3 in flight across x staging
#pragma unroll
    for (int s = 0; s < 4; ++s)
#pragma unroll
        for (int ni = 0; ni < 2; ++ni)
            pb[s][ni] = W1[(s * 16 + n32b + ni) * 64 + lane];

    float b1v[2];
    b1v[0] = b1[b * HH + (n32b + 0) * 32 + l31];
    b1v[1] = b1[b * HH + (n32b + 1) * 32 + l31];

    // stage x in A-frag order (K1 = 112), thread = (row=lane, ks1=ws)
    if (ws < 7) {
        int row = lane, s = ws;
        int mi = row >> 5, m = row & 31;
        const float* xr = x + ((size_t)(m0 + row) * BB + b) * FF + s * 16;
        u32 p[8];
#pragma unroll
        for (int i = 0; i < 8; ++i) p[i] = 0;
        if (s <= 5) {
#pragma unroll
            for (int j = 0; j < 4; ++j) {
                float4 v = *(const float4*)(xr + j * 4);
                p[j * 2 + 0] = (u32)f2bf(nan2num(v.x)) | ((u32)f2bf(nan2num(v.y)) << 16);
                p[j * 2 + 1] = (u32)f2bf(nan2num(v.z)) | ((u32)f2bf(nan2num(v.w)) << 16);
            }
        } else {                           // s == 6: k 96..99 real, rest zero
            float4 v = *(const float4*)(xr);
            p[0] = (u32)f2bf(nan2num(v.x)) | ((u32)f2bf(nan2num(v.y)) << 16);
            p[1] = (u32)f2bf(nan2num(v.z)) | ((u32)f2bf(nan2num(v.w)) << 16);
        }
        int fi1 = s * 2 + mi;
        uint4 g0 = {p[0], p[1], p[2], p[3]};
        uint4 g1 = {p[4], p[5], p[6], p[7]};
        *(uint4*)(xf + (fi1 * 64 + m) * 8)      = g0;
        *(uint4*)(xf + (fi1 * 64 + 32 + m) * 8) = g1;
    }
    __syncthreads();

    // layer 1: 7 k-steps (K=112)
    f32x16 acc1[2][2] = {};
#pragma unroll
    for (int s = 0; s < 2; ++s)
#pragma unroll
        for (int mi = 0; mi < 2; ++mi)
            pa[s][mi] = *(const bf16x8*)(xf + ((s * 2 + mi) * 64 + lane) * 8);
#pragma unroll
    for (int ks = 0; ks < 7; ++ks) {
        const int pA = ks & 1, pB = ks & 3;
        bf16x8 a0 = pa[pA][0], a1 = pa[pA][1];
        bf16x8 b0 = pb[pB][0], b1r = pb[pB][1];
        if (ks < 5) {
#pragma unroll
            for (int mi = 0; mi < 2; ++mi)
                pa[pA][mi] = *(const bf16x8*)(xf + (((ks + 2) * 2 + mi) * 64 + lane) * 8);
        }
        if (ks < 3) {
#pragma unroll
            for (int ni = 0; ni < 2; ++ni)
                pb[pB][ni] = W1[((ks + 4) * 16 + n32b + ni) * 64 + lane];
        }
        acc1[0][0] = __builtin_amdgcn_mfma_f32_32x32x16_bf16(a0, b0,  acc1[0][0], 0, 0, 0);
        acc1[0][1] = __builtin_amdgcn_mfma_f32_32x32x16_bf16(a0, b1r, acc1[0][1], 0, 0, 0);
        acc1[1][0] = __builtin_amdgcn_mfma_f32_32x32x16_bf16(a1, b0,  acc1[1][0], 0, 0, 0);
        acc1[1][1] = __builtin_amdgcn_mfma_f32_32x32x16_bf16(a1, b1r, acc1[1][1], 0, 0, 0);
    }

    // epilogue: relu(acc1+b1) -> h1f in A-frag order
    {
        char* hw = (char*)h1f + (l31 >> 4) * 2048 + ((l31 >> 3) & 1) * 512 +
                   (l31 & 6) * 2 + lh * 64 + n32b * 4096;
#pragma unroll
        for (int ni = 0; ni < 2; ++ni) {
#pragma unroll
            for (int mi = 0; mi < 2; ++mi)
#pragma unroll
                for (int qd = 0; qd < 4; ++qd) {
                    u32 own01 = (u32)f2bf(fmaxf(acc1[mi][ni][qd * 4 + 0] + b1v[ni], 0.f)) |
                                ((u32)f2bf(fmaxf(acc1[mi][ni][qd * 4 + 1] + b1v[ni], 0.f)) << 16);
                    u32 own23 = (u32)f2bf(fmaxf(acc1[mi][ni][qd * 4 + 2] + b1v[ni], 0.f)) |
                                ((u32)f2bf(fmaxf(acc1[mi][ni][qd * 4 + 3] + b1v[ni], 0.f)) << 16);
                    u32 oth01 = __shfl_xor(own01, 1, 64);
                    u32 oth23 = __shfl_xor(own23, 1, 64);
                    char* base = hw + ni * 4096 + mi * 1024 + qd * 128;
                    if (!(lane & 1)) {
                        *(u32*)(base +  0) = (own01 & 0xffffu) | (oth01 << 16);
                        *(u32*)(base + 16) = (own01 >> 16) | (oth01 & 0xffff0000u);
                    } else {
                        *(u32*)(base + 32) = (oth23 & 0xffffu) | (own23 << 16);
                        *(u32*)(base + 48) = (oth23 >> 16) | (own23 & 0xffff0000u);
                    }
                }
        }
    }
    __syncthreads();

    // coalesced copy-out: 64 KB tile -> h1g
    {
        const uint4* src = (const uint4*)h1f;
        uint4* dst = (uint4*)(h1g + (size_t)(b * 128 + blockIdx.y) * 32768);
#pragma unroll
        for (int j = 0; j < 8; ++j)
            dst[tid + j * 512] = src[tid + j * 512];
    }
}

// ---- kernel B: layer 2+3 from global h1 (frag-major), barrier-free loop ---
__global__ __launch_bounds__(512, 4) void l23_kernel(
    const u16* __restrict__ h1g, const u16* __restrict__ w2f,
    const float* __restrict__ b2, const float* __restrict__ w3,
    const float* __restrict__ b3, float* __restrict__ out) {
    __shared__ float part[512];            // cross-wave reduce only (2 KB)

    const int tid = threadIdx.x;
    const int b = blockIdx.x;              // batch -> XCD affinity
    const int m0 = blockIdx.y * 64;
    const int lane = tid & 63;
    const int ws = __builtin_amdgcn_readfirstlane(tid >> 6);
    const int l31 = lane & 31, lh = lane >> 5;
    const int n32b = ws * 2;

    const bf16x8* W2 = (const bf16x8*)w2f + (size_t)b * 32768;
    // A-frag base for this tile: all 8 waves share this stream (L1 broadcast)
    const char* Ab = (const char*)(h1g + (size_t)(b * 128 + blockIdx.y) * 32768) +
                     (size_t)lane * 16;

    bf16x8 pa[2][2], pb[4][2];

    // B prologue: stages 0..3
#pragma unroll
    for (int s = 0; s < 4; ++s)
#pragma unroll
        for (int ni = 0; ni < 2; ++ni)
            pb[s][ni] = W2[(s * 16 + n32b + ni) * 64 + lane];

    // layer-3 coefficients (independent loads, hidden under loop)
    float b2v[2], w3v[2];
#pragma unroll
    for (int ni = 0; ni < 2; ++ni) {
        int n = (n32b + ni) * 32 + l31;
        b2v[ni] = b2[b * HH + n];
        w3v[ni] = w3[b * HH + n];
    }

    // A prologue: stages 0,1
#pragma unroll
    for (int s = 0; s < 2; ++s)
#pragma unroll
        for (int mi = 0; mi < 2; ++mi)
            pa[s][mi] = *(const bf16x8*)(Ab + (s * 2 + mi) * 1024);

    // main loop: 32 k-steps, zero barriers
    f32x16 acc2[2][2] = {};
#pragma unroll
    for (int ks = 0; ks < 32; ++ks) {
        const int pA = ks & 1, pB = ks & 3;
        bf16x8 a0 = pa[pA][0], a1 = pa[pA][1];
        bf16x8 b0 = pb[pB][0], b1r = pb[pB][1];
        if (ks < 30) {
#pragma unroll
            for (int mi = 0; mi < 2; ++mi)
                pa[pA][mi] = *(const bf16x8*)(Ab + ((ks + 2) * 2 + mi) * 1024);
        }
        if (ks < 28) {
#pragma unroll
            for (int ni = 0; ni < 2; ++ni)
                pb[pB][ni] = W2[((ks + 4) * 16 + n32b + ni) * 64 + lane];
        }
        acc2[0][0] = __builtin_amdgcn_mfma_f32_32x32x16_bf16(a0, b0,  acc2[0][0], 0, 0, 0);
        acc2[0][1] = __builtin_amdgcn_mfma_f32_32x32x16_bf16(a0, b1r, acc2[0][1], 0, 0, 0);
        acc2[1][0] = __builtin_amdgcn_mfma_f32_32x32x16_bf16(a1, b0,  acc2[1][0], 0, 0, 0);
        acc2[1][1] = __builtin_amdgcn_mfma_f32_32x32x16_bf16(a1, b1r, acc2[1][1], 0, 0, 0);
    }

    // layer 3: fold, reduce over 32 cols, cross-wave via LDS
#pragma unroll
    for (int mi = 0; mi < 2; ++mi)
#pragma unroll
        for (int r = 0; r < 16; ++r) {
            float v = fmaxf(acc2[mi][0][r] + b2v[0], 0.f) * w3v[0] +
                      fmaxf(acc2[mi][1][r] + b2v[1], 0.f) * w3v[1];
            v += __shfl_xor(v, 1, 64);
            v += __shfl_xor(v, 2, 64);
            v += __shfl_xor(v, 4, 64);
            v += __shfl_xor(v, 8, 64);
            v += __shfl_xor(v, 16, 64);
            if (l31 == 0)
                part[ws * 64 + mi * 32 + (r & 3) + 8 * (r >> 2) + 4 * lh] = v;
        }
    __syncthreads();
    if (tid < 64) {
        float s = b3[b];
#pragma unroll
        for (int ww = 0; ww < 8; ++ww) s += part[ww * 64 + tid];
        out[(size_t)(m0 + tid) * BB + b] = s;
    }
}

extern "C" void kernel_launch(void* const* d_in, const int* in_sizes, int n_in,
                              void* d_out, int out_size, void* d_ws, size_t ws_size,
                              hipStream_t stream) {
    const float* x  = (const float*)d_in[0];
    const float* w1 = (const float*)d_in[1];
    const float* b1 = (const float*)d_in[2];
    const float* w2 = (const float*)d_in[3];
    const float* b2 = (const float*)d_in[4];
    const float* w3 = (const float*)d_in[5];
    const float* b3 = (const float*)d_in[6];
    float* out = (float*)d_out;

    u16* w1f = (u16*)d_ws;                              // 1 MB
    u16* w2f = w1f + (size_t)BB * 8192 * 8;             // 4 MB
    u16* h1g = w2f + (size_t)BB * 32768 * 8;            // 64 MB (frag-major h1)

    prep_w<<<1280, 256, 0, stream>>>(w1, w2, w1f, w2f);
    l1_kernel<<<dim3(BB, T_TEST / 64), 512, 0, stream>>>(x, w1f, b1, h1g);
    l23_kernel<<<dim3(BB, T_TEST / 64), 512, 0, stream>>>(h1g, w2f, b2, w3, b3, out);
}

// Round 12
// 142.292 us; speedup vs baseline: 1.1012x; 1.1012x over previous
//
#include <hip/hip_runtime.h>

#define T_TEST 8192
#define BB 8
#define FF 100
#define HH 512

typedef __bf16 bf16x8 __attribute__((ext_vector_type(8)));
typedef float f32x16 __attribute__((ext_vector_type(16)));
typedef unsigned short u16;
typedef unsigned int u32;

__device__ __forceinline__ u16 f2bf(float f) {
    u32 u = __float_as_uint(f);
    u += 0x7fffu + ((u >> 16) & 1);   // RNE
    return (u16)(u >> 16);
}

__device__ __forceinline__ float nan2num(float v) {
    u32 u = __float_as_uint(v);
    if ((u & 0x7f800000u) == 0x7f800000u) {
        v = (u & 0x007fffffu) ? 0.f : ((u >> 31) ? -3.3895314e38f : 3.3895314e38f);
    }
    return v;
}

// ---- combined weight prep: 32x32x16 fragment-major layouts (unchanged) --
// B-frag: B[k][n], n = lane&31, k = (lane>>5)*8 + j, 8 bf16/lane.
// w1f frag idx: ((b*8  + ks)*16 + n32)*64 + lane   (ks 0..7; kernel uses 0..6)
// w2f frag idx: ((b*32 + ks)*16 + n32)*64 + lane   (ks 0..31)
__global__ void prep_w(const float* __restrict__ w1, const float* __restrict__ w2,
                       u16* __restrict__ w1f, u16* __restrict__ w2f) {
    int bid = blockIdx.x;
    if (bid < 256) {                      // w1f
        int t = bid * 256 + threadIdx.x;
        int lane = t & 63;
        int n32 = (t >> 6) & 15;
        int b = t >> 13;
        int n = n32 * 32 + (lane & 31);
        int kb = ((t >> 10) & 7) * 16 + (lane >> 5) * 8;
        u32 p[4];
#pragma unroll
        for (int jp = 0; jp < 4; ++jp) {
            int k0 = kb + jp * 2;
            float v0 = (k0 < FF)     ? w1[(b * FF + k0) * HH + n]     : 0.f;
            float v1 = (k0 + 1 < FF) ? w1[(b * FF + k0 + 1) * HH + n] : 0.f;
            p[jp] = (u32)f2bf(v0) | ((u32)f2bf(v1) << 16);
        }
        uint4 o = {p[0], p[1], p[2], p[3]};
        *(uint4*)(w1f + (size_t)t * 8) = o;
    } else {                              // w2f
        int t = (bid - 256) * 256 + threadIdx.x;
        int lane = t & 63;
        int n32 = (t >> 6) & 15;
        int b = t >> 15;
        int n = n32 * 32 + (lane & 31);
        int kb = ((t >> 10) & 31) * 16 + (lane >> 5) * 8;
        u32 p[4];
#pragma unroll
        for (int jp = 0; jp < 4; ++jp) {
            int k0 = kb + jp * 2;
            float v0 = w2[(b * HH + k0) * HH + n];
            float v1 = w2[(b * HH + k0 + 1) * HH + n];
            p[jp] = (u32)f2bf(v0) | ((u32)f2bf(v1) << 16);
        }
        uint4 o = {p[0], p[1], p[2], p[3]};
        *(uint4*)(w2f + (size_t)t * 8) = o;
    }
}

// ---- fused 3-layer MLP: 32 rows/block, 8 waves (2 n32 each, mi=1), ------
// ---- 40 KB LDS + <=85 regs/wave -> 24 waves/CU (6/SIMD): TLP bet --------
__global__ __launch_bounds__(512, 6) void fused_mlp(
    const float* __restrict__ x, const u16* __restrict__ w1f,
    const float* __restrict__ b1, const u16* __restrict__ w2f,
    const float* __restrict__ b2, const float* __restrict__ w3,
    const float* __restrict__ b3, float* __restrict__ out) {
    __shared__ __align__(16) char lds[40960];
    u16* xf  = (u16*)lds;                  // x frags, 8 KB  (fi = ks1, 1 KB each)
    u16* h1f = (u16*)(lds + 8192);         // h1 frags, 32 KB (fi = ks, 1 KB each)

    const int tid = threadIdx.x;
    const int b = blockIdx.x;              // batch -> XCD affinity
    const int m0 = blockIdx.y * 32;
    const int lane = tid & 63;
    const int ws = __builtin_amdgcn_readfirstlane(tid >> 6);
    const int l31 = lane & 31, lh = lane >> 5;
    const int n32b = ws * 2;
    const int r2 = ws * 4;                 // layer-2 K-phase

    const bf16x8* W1 = (const bf16x8*)w1f + (size_t)b * 8192;
    const bf16x8* W2 = (const bf16x8*)w2f + (size_t)b * 32768;

    bf16x8 pa[2], pb[2][2];

    // layer-1 B prologue (ring-2): stages 0,1 in flight across x staging
#pragma unroll
    for (int s = 0; s < 2; ++s)
#pragma unroll
        for (int ni = 0; ni < 2; ++ni)
            pb[s][ni] = W1[(s * 16 + n32b + ni) * 64 + lane];

    float b1v[2];
    b1v[0] = b1[b * HH + (n32b + 0) * 32 + l31];
    b1v[1] = b1[b * HH + (n32b + 1) * 32 + l31];

    // ---- stage x in A-frag order: thread = (row = tid&31, s = tid>>5) ----
    {
        int row = tid & 31, s = tid >> 5;      // s in [0,16), frags 0..6 used
        if (s < 7) {
            const float* xr = x + ((size_t)(m0 + row) * BB + b) * FF + s * 16;
            u32 p[8];
#pragma unroll
            for (int i = 0; i < 8; ++i) p[i] = 0;
            if (s <= 5) {
#pragma unroll
                for (int j = 0; j < 4; ++j) {
                    float4 v = *(const float4*)(xr + j * 4);
                    p[j * 2 + 0] = (u32)f2bf(nan2num(v.x)) | ((u32)f2bf(nan2num(v.y)) << 16);
                    p[j * 2 + 1] = (u32)f2bf(nan2num(v.z)) | ((u32)f2bf(nan2num(v.w)) << 16);
                }
            } else {                           // s == 6: k 96..99 real, rest zero
                float4 v = *(const float4*)(xr);
                p[0] = (u32)f2bf(nan2num(v.x)) | ((u32)f2bf(nan2num(v.y)) << 16);
                p[1] = (u32)f2bf(nan2num(v.z)) | ((u32)f2bf(nan2num(v.w)) << 16);
            }
            uint4 g0 = {p[0], p[1], p[2], p[3]};
            uint4 g1 = {p[4], p[5], p[6], p[7]};
            *(uint4*)(xf + (s * 64 + row) * 8)      = g0;   // khalf 0
            *(uint4*)(xf + (s * 64 + 32 + row) * 8) = g1;   // khalf 1
        }
    }
    __syncthreads();

    // ---- layer 1: 7 k-steps (K=112), pa ring-2, pb ring-2 ----
    f32x16 acc1[2] = {};
    pa[0] = *(const bf16x8*)(xf + (0 * 64 + lane) * 8);
    pa[1] = *(const bf16x8*)(xf + (1 * 64 + lane) * 8);
#pragma unroll
    for (int ks = 0; ks < 7; ++ks) {
        const int p = ks & 1;
        bf16x8 a0 = pa[p];
        bf16x8 b0 = pb[p][0], b1r = pb[p][1];
        if (ks < 5) {
            pa[p] = *(const bf16x8*)(xf + ((ks + 2) * 64 + lane) * 8);
#pragma unroll
            for (int ni = 0; ni < 2; ++ni)
                pb[p][ni] = W1[((ks + 2) * 16 + n32b + ni) * 64 + lane];
        }
        acc1[0] = __builtin_amdgcn_mfma_f32_32x32x16_bf16(a0, b0,  acc1[0], 0, 0, 0);
        acc1[1] = __builtin_amdgcn_mfma_f32_32x32x16_bf16(a0, b1r, acc1[1], 0, 0, 0);
    }

    // layer-2 B prologue (ring-2): stages r2, r2+1 in flight across epilogue
#pragma unroll
    for (int s = 0; s < 2; ++s) {
        int k = (r2 + s) & 31;
#pragma unroll
        for (int ni = 0; ni < 2; ++ni)
            pb[s][ni] = W2[(k * 16 + n32b + ni) * 64 + lane];
    }

    // ---- epilogue 1: relu(acc1+b1) -> h1f in A-frag order ----
    // h1 col n -> layer-2 k: fi = n>>4 = n32*2 + (l31>>4); row = qd*8+lh*4+rr.
    {
        char* hw = (char*)h1f + n32b * 2048 + (l31 >> 4) * 1024 +
                   ((l31 >> 3) & 1) * 512 + (l31 & 6) * 2 + lh * 64;
#pragma unroll
        for (int ni = 0; ni < 2; ++ni) {
#pragma unroll
            for (int qd = 0; qd < 4; ++qd) {
                u32 own01 = (u32)f2bf(fmaxf(acc1[ni][qd * 4 + 0] + b1v[ni], 0.f)) |
                            ((u32)f2bf(fmaxf(acc1[ni][qd * 4 + 1] + b1v[ni], 0.f)) << 16);
                u32 own23 = (u32)f2bf(fmaxf(acc1[ni][qd * 4 + 2] + b1v[ni], 0.f)) |
                            ((u32)f2bf(fmaxf(acc1[ni][qd * 4 + 3] + b1v[ni], 0.f)) << 16);
                u32 oth01 = __shfl_xor(own01, 1, 64);
                u32 oth23 = __shfl_xor(own23, 1, 64);
                char* base = hw + ni * 2048 + qd * 128;
                if (!(lane & 1)) {
                    *(u32*)(base +  0) = (own01 & 0xffffu) | (oth01 << 16);      // rr=0
                    *(u32*)(base + 16) = (own01 >> 16) | (oth01 & 0xffff0000u);  // rr=1
                } else {
                    *(u32*)(base + 32) = (oth23 & 0xffffu) | (own23 << 16);      // rr=2
                    *(u32*)(base + 48) = (oth23 >> 16) | (own23 & 0xffff0000u);  // rr=3
                }
            }
        }
    }
    __syncthreads();

    // hoist layer-3 coefficients (latency hidden under layer 2)
    float b2v[2], w3v[2];
#pragma unroll
    for (int ni = 0; ni < 2; ++ni) {
        int n = (n32b + ni) * 32 + l31;
        b2v[ni] = b2[b * HH + n];
        w3v[ni] = w3[b * HH + n];
    }

    // ---- layer 2: 32 k-steps, K-phase r2, pa ring-2, pb ring-2 ----
    f32x16 acc2[2] = {};
    const char* hv  = (const char*)h1f + r2 * 1024 + (size_t)lane * 16;
    const char* hvB = hv - 32768;
#pragma unroll
    for (int s = 0; s < 2; ++s) {
        const char* hp = (s + r2 < 32) ? hv : hvB;
        pa[s] = *(const bf16x8*)(hp + s * 1024);
    }
#pragma unroll
    for (int ks = 0; ks < 32; ++ks) {
        const int p = ks & 1;
        bf16x8 a0 = pa[p];
        bf16x8 b0 = pb[p][0], b1r = pb[p][1];
        if (ks < 30) {
            const char* hp = (ks + 2 + r2 < 32) ? hv : hvB;
            pa[p] = *(const bf16x8*)(hp + (ks + 2) * 1024);
            int kspf = ks + 2 + r2;
            kspf -= (kspf >= 32) ? 32 : 0;
#pragma unroll
            for (int ni = 0; ni < 2; ++ni)
                pb[p][ni] = W2[(kspf * 16 + n32b + ni) * 64 + lane];
        }
        acc2[0] = __builtin_amdgcn_mfma_f32_32x32x16_bf16(a0, b0,  acc2[0], 0, 0, 0);
        acc2[1] = __builtin_amdgcn_mfma_f32_32x32x16_bf16(a0, b1r, acc2[1], 0, 0, 0);
    }

    // ---- layer 3: fold, reduce over 32 cols, cross-wave via LDS ----
    float* part = (float*)xf;              // [8][32]; x frags dead
#pragma unroll
    for (int r = 0; r < 16; ++r) {
        float v = fmaxf(acc2[0][r] + b2v[0], 0.f) * w3v[0] +
                  fmaxf(acc2[1][r] + b2v[1], 0.f) * w3v[1];
        v += __shfl_xor(v, 1, 64);
        v += __shfl_xor(v, 2, 64);
        v += __shfl_xor(v, 4, 64);
        v += __shfl_xor(v, 8, 64);
        v += __shfl_xor(v, 16, 64);
        if (l31 == 0)
            part[ws * 32 + (r & 3) + 8 * (r >> 2) + 4 * lh] = v;
    }
    __syncthreads();
    if (tid < 32) {
        float s = b3[b];
#pragma unroll
        for (int ww = 0; ww < 8; ++ww) s += part[ww * 32 + tid];
        out[(size_t)(m0 + tid) * BB + b] = s;
    }
}

extern "C" void kernel_launch(void* const* d_in, const int* in_sizes, int n_in,
                              void* d_out, int out_size, void* d_ws, size_t ws_size,
                              hipStream_t stream) {
    const float* x  = (const float*)d_in[0];
    const float* w1 = (const float*)d_in[1];
    const float* b1 = (const float*)d_in[2];
    const float* w2 = (const float*)d_in[3];
    const float* b2 = (const float*)d_in[4];
    const float* w3 = (const float*)d_in[5];
    const float* b3 = (const float*)d_in[6];
    float* out = (float*)d_out;

    u16* w1f = (u16*)d_ws;                              // 1 MB
    u16* w2f = w1f + (size_t)BB * 8192 * 8;             // 4 MB

    prep_w<<<1280, 256, 0, stream>>>(w1, w2, w1f, w2f);

    // grid.x = batch (XCD affinity), grid.y = 32-row tile
    fused_mlp<<<dim3(BB, T_TEST / 32), 512, 0, stream>>>(
        x, w1f, b1, w2f, b2, w3, b3, out);
}